// Round 3
// baseline (973.407 us; speedup 1.0000x reference)
//
#include <hip/hip_runtime.h>

#define L 2048
#define B 64
#define D_DEC 1024
#define D_ALIGN 512
#define D_ENC 1024

using u32 = unsigned int;
using u16 = unsigned short;

__device__ __forceinline__ u16 f2bf(float f) {
    u32 u = __float_as_uint(f);
    u32 r = (u + 0x7fffu + ((u >> 16) & 1u)) >> 16;   // RNE
    return (u16)r;
}
__device__ __forceinline__ float tanh_fast(float x) {
    float t = __expf(2.0f * x);
    return 1.0f - 2.0f * __builtin_amdgcn_rcpf(t + 1.0f);
}
// xs_mask row 0 is exactly 1.0 for all 64 b -> word0 is 0x3F803F80 iff bf16
__device__ __forceinline__ bool detect_bf(const void* xs_mask) {
    return ((const u32*)xs_mask)[0] == 0x3F803F80u;
}
__device__ __forceinline__ float ldv(const void* p, size_t i, bool bf) {
    if (bf) return __uint_as_float(((u32)((const u16*)p)[i]) << 16);
    return ((const float*)p)[i];
}

// proj[b*512+a] = dot(s_tm1[b,:], sa_w[a,:]) + sa_b[a]
__global__ __launch_bounds__(256) void proj_kernel(const void* __restrict__ s_tm1,
                                                   const void* __restrict__ sa_w,
                                                   const void* __restrict__ c0,
                                                   const void* __restrict__ c1,
                                                   const void* __restrict__ xs_mask,
                                                   float* __restrict__ proj) {
    bool bf = detect_bf(xs_mask);
    u32 w0 = ((const u32*)c0)[0], w1 = ((const u32*)c1)[0];
    const void* sab = (w0 == 0u || w1 != 0u) ? c0 : c1;   // sa_b is the all-zero one
    int idx = blockIdx.x * 256 + threadIdx.x;             // 32768
    int b = idx >> 9, a = idx & 511;
    size_t sbase = (size_t)b * D_DEC, wbase = (size_t)a * D_DEC;
    float acc = 0.f;
#pragma unroll 8
    for (int k = 0; k < D_DEC; ++k)
        acc += ldv(s_tm1, sbase + k, bf) * ldv(sa_w, wbase + k, bf);
    proj[idx] = acc + ldv(sab, a, bf);
}

// score[l*B+b] = sum_a tanh(proj[b,a]+uh[l,b,a]) * a1_w[a] + a1_b
// wave handles 8 consecutive l for fixed b; lane covers a = j*64+lane (coalesced)
__global__ __launch_bounds__(256) void score_kernel(const void* __restrict__ uh,
                                                    const void* __restrict__ c0,
                                                    const void* __restrict__ c1,
                                                    const void* __restrict__ a1_b,
                                                    const void* __restrict__ xs_mask,
                                                    const float* __restrict__ proj,
                                                    float* __restrict__ score) {
    bool bf = detect_bf(xs_mask);
    u32 w0 = ((const u32*)c0)[0], w1 = ((const u32*)c1)[0];
    const void* a1w = (w1 != 0u || w0 == 0u) ? c1 : c0;   // a1_w is the nonzero one
    int wave = blockIdx.x * 4 + (threadIdx.x >> 6);       // 16384 waves
    int lane = threadIdx.x & 63;
    int b = wave & (B - 1);
    int lc = wave >> 6;                                   // 0..255
    float p[8], w[8];
#pragma unroll
    for (int j = 0; j < 8; ++j) {
        p[j] = proj[b * D_ALIGN + j * 64 + lane];
        w[j] = ldv(a1w, j * 64 + lane, bf);
    }
    float bias = ldv(a1_b, 0, bf);
    float s[8];
#pragma unroll
    for (int il = 0; il < 8; ++il) {
        int l = lc * 8 + il;
        size_t base = (size_t)(l * B + b) * D_ALIGN;
        float v = 0.f;
#pragma unroll
        for (int j = 0; j < 8; ++j)
            v += tanh_fast(p[j] + ldv(uh, base + j * 64 + lane, bf)) * w[j];
        s[il] = v;
    }
#pragma unroll
    for (int il = 0; il < 8; ++il) {
        float v = s[il];
        for (int off = 32; off; off >>= 1) v += __shfl_xor(v, off, 64);
        s[il] = v;
    }
    if (lane == 0) {
#pragma unroll
        for (int il = 0; il < 8; ++il)
            score[(lc * 8 + il) * B + b] = s[il] + bias;
    }
}

// masked softmax over l per column b; e_ij -> out (dtype-matched) + fp32 copy to ws
__global__ __launch_bounds__(256) void softmax_kernel(const void* __restrict__ xs_mask,
                                                      const float* __restrict__ score,
                                                      float* __restrict__ e_norm,
                                                      void* __restrict__ out) {
    bool bf = detect_bf(xs_mask);
    int b = blockIdx.x;
    int tid = threadIdx.x;
    __shared__ float red[256];
    float s[8];
    float mx = -1e30f;
#pragma unroll
    for (int i = 0; i < 8; ++i) {
        int l = tid + i * 256;
        s[i] = score[l * B + b];
        mx = fmaxf(mx, s[i]);
    }
    red[tid] = mx; __syncthreads();
    for (int off = 128; off; off >>= 1) {
        if (tid < off) red[tid] = fmaxf(red[tid], red[tid + off]);
        __syncthreads();
    }
    mx = red[0]; __syncthreads();
    float sum = 0.f;
#pragma unroll
    for (int i = 0; i < 8; ++i) {
        int l = tid + i * 256;
        s[i] = __expf(s[i] - mx) * ldv(xs_mask, (size_t)l * B + b, bf);
        sum += s[i];
    }
    red[tid] = sum; __syncthreads();
    for (int off = 128; off; off >>= 1) {
        if (tid < off) red[tid] += red[tid + off];
        __syncthreads();
    }
    float inv = 1.0f / red[0];
#pragma unroll
    for (int i = 0; i < 8; ++i) {
        int l = tid + i * 256;
        float e = s[i] * inv;
        e_norm[l * B + b] = e;
        if (bf) ((u16*)out)[l * B + b] = f2bf(e);
        else    ((float*)out)[l * B + b] = e;
    }
}

// attend partial: block=(b, l-split of 128); thread covers d = tid + j*256 (coalesced)
__global__ __launch_bounds__(256) void attend_kernel(const void* __restrict__ xs_h,
                                                     const void* __restrict__ xs_mask,
                                                     const float* __restrict__ e_norm,
                                                     float* __restrict__ acc) {
    bool bf = detect_bf(xs_mask);
    int b = blockIdx.x & (B - 1);
    int ls = blockIdx.x >> 6;            // 0..15
    int tid = threadIdx.x;
    float a[4] = {0.f, 0.f, 0.f, 0.f};
    int lbeg = ls * (L / 16), lend = lbeg + (L / 16);
    for (int l = lbeg; l < lend; ++l) {
        float w = e_norm[l * B + b];
        size_t base = (size_t)(l * B + b) * D_ENC;
#pragma unroll
        for (int j = 0; j < 4; ++j)
            a[j] += w * ldv(xs_h, base + tid + j * 256, bf);
    }
#pragma unroll
    for (int j = 0; j < 4; ++j)
        atomicAdd(acc + b * D_ENC + tid + j * 256, a[j]);
}

__global__ __launch_bounds__(256) void finalize_kernel(const float* __restrict__ acc,
                                                       const void* __restrict__ xs_mask,
                                                       void* __restrict__ out) {
    bool bf = detect_bf(xs_mask);
    int i = blockIdx.x * 256 + threadIdx.x;   // 65536
    if (bf) ((u16*)out)[(size_t)L * B + i] = f2bf(acc[i]);
    else    ((float*)out)[(size_t)L * B + i] = acc[i];
}

extern "C" void kernel_launch(void* const* d_in, const int* in_sizes, int n_in,
                              void* d_out, int out_size, void* d_ws, size_t ws_size,
                              hipStream_t stream) {
    // documented dict order as defaults
    const void *s_tm1 = d_in[0], *xs_h = d_in[1], *uh = d_in[2], *xs_mask = d_in[3],
               *sa_w = d_in[4];
    const void *a1_b = d_in[7];
    const void *p512[2] = {d_in[5], d_in[6]};
    int n512 = 0;
    for (int i = 0; i < n_in; ++i) {
        switch (in_sizes[i]) {
            case 134217728: xs_h = d_in[i]; break;
            case 67108864:  uh = d_in[i]; break;
            case 131072:    xs_mask = d_in[i]; break;
            case 65536:     s_tm1 = d_in[i]; break;
            case 524288:    sa_w = d_in[i]; break;
            case 1:         a1_b = d_in[i]; break;
            case 512:       if (n512 < 2) p512[n512] = d_in[i]; ++n512; break;
            default: break;
        }
    }
    const void* c0 = p512[0];   // sa_b per documented order (all zeros)
    const void* c1 = p512[1];   // a1_w per documented order

    char* ws = (char*)d_ws;
    float* proj   = (float*)(ws);                       // 32768 f  = 128 KB
    float* score  = (float*)(ws + 131072);              // 131072 f = 512 KB
    float* e_norm = (float*)(ws + 131072 + 524288);     // 131072 f = 512 KB
    float* acc    = (float*)(ws + 131072 + 1048576);    // 65536 f  = 256 KB

    hipMemsetAsync(acc, 0, D_ENC * B * sizeof(float), stream);

    proj_kernel<<<128, 256, 0, stream>>>(s_tm1, sa_w, c0, c1, xs_mask, proj);
    score_kernel<<<4096, 256, 0, stream>>>(uh, c0, c1, a1_b, xs_mask, proj, score);
    softmax_kernel<<<B, 256, 0, stream>>>(xs_mask, score, e_norm, d_out);
    attend_kernel<<<1024, 256, 0, stream>>>(xs_h, xs_mask, e_norm, acc);
    finalize_kernel<<<256, 256, 0, stream>>>(acc, xs_mask, d_out);
}